// Round 22
// baseline (364.550 us; speedup 1.0000x reference)
//
#include <hip/hip_runtime.h>

// B=65536, Q=128, S=8, U=32
// R22: MEASUREMENT ROUND. divenc_pA = R19 x2 passes (counters for the 82us
// anchor); divenc_pB = R19 + xs-dbuf ONLY (depth-2 load pipeline, single
// change) x2 passes; divenc_wreg = R19 exact. Distinct names so top-5 shows
// each probe. All write identical out (deterministic).
#define Q    128
#define S    8
#define U    32
#define QW   8
#define TROWS 64
#define RPB  1024
#define NTILE (RPB / TROWS)
#define RSTRIDE 272
#define XSBUF (TROWS * RSTRIDE)
#define OSS  20

typedef __attribute__((ext_vector_type(8)))  __bf16 bf16x8;
typedef __attribute__((ext_vector_type(16))) float  f32x16;
typedef __attribute__((ext_vector_type(2)))  float  f32x2;

__device__ inline unsigned short f2bf(float f) {
    unsigned int u = __float_as_uint(f);
    u += 0x7FFF + ((u >> 16) & 1);
    return (unsigned short)(u >> 16);
}

__device__ inline unsigned int cvt_pk_bf16(float lo, float hi) {
    unsigned int r;
    asm("v_cvt_pk_bf16_f32 %0, %1, %2" : "=v"(r) : "v"(lo), "v"(hi));
    return r;
}

__global__ void prep_kernel(const float* __restrict__ W1, const float* __restrict__ b1,
                            const float* __restrict__ W2, const float* __restrict__ b2,
                            unsigned short* __restrict__ W1T,
                            float* __restrict__ b1F, float* __restrict__ w2F,
                            float* __restrict__ b2F)
{
    const int q = blockIdx.x, t = threadIdx.x;
    const int u = t & 31, s = t >> 5;
    W1T[(q * 32 + u) * 8 + s] = f2bf(W1[(q * 8 + s) * 32 + u]);
    if (t < 32) {
        int reg = t & 15, hh = t >> 4;
        int uu  = (reg & 3) + 8 * (reg >> 2) + 4 * hh;
        b1F[(q * 2 + hh) * 16 + reg] = b1[q * 32 + uu] + 1.0f;
        w2F[(q * 2 + hh) * 16 + reg] = W2[q * 32 + uu];
    }
    if (t == 0) {
        float sw = 0.f;
        for (int uu = 0; uu < 32; ++uu) sw += W2[q * 32 + uu];
        b2F[q] = b2[q] - sw;
    }
}

// ---- shared body macros (reference kernel-local names) ----
#define PREAMBLE(NXBUF)                                                              \
    const int t    = threadIdx.x;                                                    \
    const int lane = t & 63;                                                         \
    const int wv   = __builtin_amdgcn_readfirstlane(t >> 6);                         \
    const int bl   = lane & 31;                                                      \
    const int h    = lane >> 5;                                                      \
    const bool lo  = (lane < 32);                                                    \
    const int bid   = blockIdx.x;                                                    \
    const int qb    = (bid & 15) * QW;                                               \
    const int rbase = (bid >> 4) * RPB;                                              \
    const int rmax  = B - 1;                                                         \
    if (t == 0) *(uint4*)(xs + (NXBUF) * XSBUF) = uint4{0, 0, 0, 0};                 \
    const int qA = qb + wv * 2, qB = qA + 1;                                         \
    const uint4  axA  = *(const uint4*)(W1T + ((size_t)qA * 32 + bl) * 8);           \
    const uint4  axB  = *(const uint4*)(W1T + ((size_t)qB * 32 + bl) * 8);           \
    const f32x16 cinA = *(const f32x16*)(b1F + ((size_t)qA * 2 + h) * 16);           \
    const f32x16 cinB = *(const f32x16*)(b1F + ((size_t)qB * 2 + h) * 16);           \
    const f32x16 wrA  = *(const f32x16*)(w2F + ((size_t)qA * 2 + h) * 16);           \
    const f32x16 wrB  = *(const f32x16*)(w2F + ((size_t)qB * 2 + h) * 16);           \
    const float  b2A  = b2F[qA], b2B = b2F[qB];                                      \
    const f32x2 l2e2  = 1.44269504088896f;                                           \
    const f32x2 nl2e2 = -1.44269504088896f;                                          \
    const f32x2 zero2 = 0.0f;                                                        \
    const int row0 = t >> 3,         qr0 = t & 7;                                    \
    const int row1 = (t + 256) >> 3, qr1 = t & 7;                                    \
    float4 pa0, pb0, pa1, pb1;

#define LOADT(T) {                                                                   \
    int r0_ = rbase + (T) * TROWS + row0; if (r0_ > rmax) r0_ = rmax;                \
    int r1_ = rbase + (T) * TROWS + row1; if (r1_ > rmax) r1_ = rmax;                \
    const float4* p0_ = (const float4*)(x + (size_t)r0_ * (Q * S)                    \
                                          + (size_t)(qb + qr0) * S);                 \
    const float4* p1_ = (const float4*)(x + (size_t)r1_ * (Q * S)                    \
                                          + (size_t)(qb + qr1) * S);                 \
    pa0 = p0_[0]; pb0 = p0_[1];                                                      \
    pa1 = p1_[0]; pb1 = p1_[1]; }

#define WRITET(XB) {                                                                 \
    uint4 w0_, w1_;                                                                  \
    w0_.x = cvt_pk_bf16(pa0.x, pa0.y); w0_.y = cvt_pk_bf16(pa0.z, pa0.w);            \
    w0_.z = cvt_pk_bf16(pb0.x, pb0.y); w0_.w = cvt_pk_bf16(pb0.z, pb0.w);            \
    w1_.x = cvt_pk_bf16(pa1.x, pa1.y); w1_.y = cvt_pk_bf16(pa1.z, pa1.w);            \
    w1_.z = cvt_pk_bf16(pb1.x, pb1.y); w1_.w = cvt_pk_bf16(pb1.z, pb1.w);            \
    *(uint4*)(xs + (XB) + row0 * RSTRIDE + qr0 * 16) = w0_;                          \
    *(uint4*)(xs + (XB) + row1 * RSTRIDE + qr1 * 16) = w1_; }

#define EL2(CC, J, WR, ACC) {                                                        \
    f32x2 v_; v_.x = CC[2*(J)]; v_.y = CC[2*(J)+1];                                  \
    f32x2 w2v; w2v.x = WR[2*(J)]; w2v.y = WR[2*(J)+1];                               \
    f32x2 f_ = __builtin_elementwise_fma(v_, l2e2, nl2e2);                           \
    f_ = __builtin_elementwise_min(f_, zero2);                                       \
    f32x2 e_; e_.x = __builtin_amdgcn_exp2f(f_.x);                                   \
    e_.y = __builtin_amdgcn_exp2f(f_.y);                                             \
    f32x2 r_ = __builtin_elementwise_max(v_, e_);                                    \
    ACC = __builtin_elementwise_fma(r_, w2v, ACC); }

#define COMP(AX, CIN, WR, B2, QR, XB, ZPO) {                                         \
    const int xoff = (XB) + bl * RSTRIDE + (QR) * 16;                                \
    uint4 bx0 = *(const uint4*)(xs + (lo ? xoff                : (ZPO)));            \
    uint4 bx1 = *(const uint4*)(xs + (lo ? xoff + 32 * RSTRIDE : (ZPO)));            \
    f32x16 cc0 = __builtin_amdgcn_mfma_f32_32x32x16_bf16(                            \
        __builtin_bit_cast(bf16x8, AX), __builtin_bit_cast(bf16x8, bx0),             \
        CIN, 0, 0, 0);                                                               \
    f32x16 cc1 = __builtin_amdgcn_mfma_f32_32x32x16_bf16(                            \
        __builtin_bit_cast(bf16x8, AX), __builtin_bit_cast(bf16x8, bx1),             \
        CIN, 0, 0, 0);                                                               \
    f32x2 acc0 = 0.0f, acc1 = 0.0f;                                                  \
    EL2(cc0, 0, WR, acc0) EL2(cc0, 1, WR, acc0) EL2(cc0, 2, WR, acc0)                \
    EL2(cc0, 3, WR, acc0) EL2(cc0, 4, WR, acc0) EL2(cc0, 5, WR, acc0)                \
    EL2(cc0, 6, WR, acc0) EL2(cc0, 7, WR, acc0)                                      \
    EL2(cc1, 0, WR, acc1) EL2(cc1, 1, WR, acc1) EL2(cc1, 2, WR, acc1)                \
    EL2(cc1, 3, WR, acc1) EL2(cc1, 4, WR, acc1) EL2(cc1, 5, WR, acc1)                \
    EL2(cc1, 6, WR, acc1) EL2(cc1, 7, WR, acc1)                                      \
    float a0 = acc0.x + acc0.y;                                                      \
    float a1 = acc1.x + acc1.y;                                                      \
    a0 += __shfl_xor(a0, 32);                                                        \
    a1 += __shfl_xor(a1, 32);                                                        \
    if (lo) {                                                                        \
        os[bl * OSS + (QR)]        = a0 + (B2);                                      \
        os[(bl + 32) * OSS + (QR)] = a1 + (B2);                                      \
    } }

#define STORE(T) {                                                                   \
    if (t < 128) {                                                                   \
        int row_ = t >> 1, c_ = t & 1;                                               \
        float4 o_ = *(const float4*)&os[row_ * OSS + c_ * 4];                        \
        int r_ = rbase + (T) * TROWS + row_;                                         \
        if (r_ < B)                                                                  \
            *(float4*)(out + (size_t)r_ * Q + qb + c_ * 4) = o_;                     \
    } }

// ---- probe A: R19 body, 2 passes ----
__global__ __launch_bounds__(256)
__attribute__((amdgpu_waves_per_eu(3, 4)))
void divenc_pA(const float* __restrict__ x, const unsigned short* __restrict__ W1T,
               const float* __restrict__ b1F, const float* __restrict__ w2F,
               const float* __restrict__ b2F, float* __restrict__ out, int B)
{
    __shared__ __align__(16) unsigned char xs[XSBUF + 16];
    __shared__ __align__(16) float os[TROWS * OSS];
    PREAMBLE(1)
    #pragma unroll 1
    for (int pass = 0; pass < 2; ++pass) {
        LOADT(0) WRITET(0)
        #pragma unroll 1
        for (int tile = 0; tile < NTILE; ++tile) {
            __syncthreads();
            if (tile + 1 < NTILE) LOADT(tile + 1)
            COMP(axA, cinA, wrA, b2A, wv * 2,     0, XSBUF)
            COMP(axB, cinB, wrB, b2B, wv * 2 + 1, 0, XSBUF)
            __syncthreads();
            STORE(tile)
            if (tile + 1 < NTILE) WRITET(0)
        }
    }
}

// ---- probe B: xs double-buffer ONLY (depth-2 pipeline), 2 passes ----
__global__ __launch_bounds__(256)
__attribute__((amdgpu_waves_per_eu(3, 4)))
void divenc_pB(const float* __restrict__ x, const unsigned short* __restrict__ W1T,
               const float* __restrict__ b1F, const float* __restrict__ w2F,
               const float* __restrict__ b2F, float* __restrict__ out, int B)
{
    __shared__ __align__(16) unsigned char xs[2 * XSBUF + 16];
    __shared__ __align__(16) float os[TROWS * OSS];
    PREAMBLE(2)
    #pragma unroll 1
    for (int pass = 0; pass < 2; ++pass) {
        LOADT(0) WRITET(0)
        LOADT(1)
        #pragma unroll 1
        for (int tile = 0; tile < NTILE; ++tile) {
            __syncthreads();                  // xs[tile&1] ready; os free
            if (tile + 1 < NTILE) WRITET(((tile + 1) & 1) * XSBUF)
            if (tile + 2 < NTILE) LOADT(tile + 2)
            COMP(axA, cinA, wrA, b2A, wv * 2,     (tile & 1) * XSBUF, 2 * XSBUF)
            COMP(axB, cinB, wrB, b2B, wv * 2 + 1, (tile & 1) * XSBUF, 2 * XSBUF)
            __syncthreads();
            STORE(tile)
        }
    }
}

// ---- real kernel: R19 exact, 1 pass ----
__global__ __launch_bounds__(256)
__attribute__((amdgpu_waves_per_eu(3, 4)))
void divenc_wreg(const float* __restrict__ x, const unsigned short* __restrict__ W1T,
                 const float* __restrict__ b1F, const float* __restrict__ w2F,
                 const float* __restrict__ b2F, float* __restrict__ out, int B)
{
    __shared__ __align__(16) unsigned char xs[XSBUF + 16];
    __shared__ __align__(16) float os[TROWS * OSS];
    PREAMBLE(1)
    LOADT(0) WRITET(0)
    #pragma unroll 1
    for (int tile = 0; tile < NTILE; ++tile) {
        __syncthreads();
        if (tile + 1 < NTILE) LOADT(tile + 1)
        COMP(axA, cinA, wrA, b2A, wv * 2,     0, XSBUF)
        COMP(axB, cinB, wrB, b2B, wv * 2 + 1, 0, XSBUF)
        __syncthreads();
        STORE(tile)
        if (tile + 1 < NTILE) WRITET(0)
    }
}

extern "C" void kernel_launch(void* const* d_in, const int* in_sizes, int n_in,
                              void* d_out, int out_size, void* d_ws, size_t ws_size,
                              hipStream_t stream) {
    const float* x  = (const float*)d_in[0];
    const float* W1 = (const float*)d_in[1];
    const float* b1 = (const float*)d_in[2];
    const float* W2 = (const float*)d_in[3];
    const float* b2 = (const float*)d_in[4];
    float* out = (float*)d_out;

    unsigned short* W1T = (unsigned short*)d_ws;
    float*          b1F = (float*)((char*)d_ws + 65536);
    float*          w2F = (float*)((char*)d_ws + 81920);
    float*          b2F = (float*)((char*)d_ws + 98304);

    const int B = in_sizes[0] / (Q * S);
    const int nblocks = ((B + RPB - 1) / RPB) * (Q / QW);   // 1024

    hipLaunchKernelGGL(prep_kernel, dim3(Q), dim3(256), 0, stream,
                       W1, b1, W2, b2, W1T, b1F, w2F, b2F);
    hipLaunchKernelGGL(divenc_pA, dim3(nblocks), dim3(256), 0, stream,
                       x, W1T, b1F, w2F, b2F, out, B);
    hipLaunchKernelGGL(divenc_pB, dim3(nblocks), dim3(256), 0, stream,
                       x, W1T, b1F, w2F, b2F, out, B);
    hipLaunchKernelGGL(divenc_wreg, dim3(nblocks), dim3(256), 0, stream,
                       x, W1T, b1F, w2F, b2F, out, B);
}

// Round 23
// 82.782 us; speedup vs baseline: 4.4037x; 4.4037x over previous
//
#include <hip/hip_runtime.h>

// B=65536, Q=128, S=8, U=32
// out[b,q] = b2[q] + sum_u elu(b1[q,u] + sum_s x[b,q,s]*W1[q,s,u]) * W2[q,u]
//
// R23 = R22's divenc_pB structure, single pass (MEASURED ~41us/pass in R22):
//  weights-in-registers (R18) + xs DOUBLE-buffer depth-2 load pipeline:
//  at tile t: barrier; WRITET(t+1) (loads from t-1 have a FULL tile of slack);
//  LOADT(t+2) issues; COMP(t); barrier; STORE(t). R20's regression was the
//  bundled RSTRIDE/os changes, not dbuf - this keeps RSTRIDE 272 / OSS 20 /
//  2 barriers exactly as measured.
#define Q    128
#define S    8
#define U    32
#define QW   8
#define TROWS 64
#define RPB  1024
#define NTILE (RPB / TROWS)     // 16
#define RSTRIDE 272
#define XSBUF (TROWS * RSTRIDE) // 17408
#define ZOFF  (2 * XSBUF)       // zero page after both xs buffers
#define OSS  20

typedef __attribute__((ext_vector_type(8)))  __bf16 bf16x8;
typedef __attribute__((ext_vector_type(16))) float  f32x16;
typedef __attribute__((ext_vector_type(2)))  float  f32x2;

__device__ inline unsigned short f2bf(float f) {
    unsigned int u = __float_as_uint(f);
    u += 0x7FFF + ((u >> 16) & 1);
    return (unsigned short)(u >> 16);
}

__device__ inline unsigned int cvt_pk_bf16(float lo, float hi) {
    unsigned int r;
    asm("v_cvt_pk_bf16_f32 %0, %1, %2" : "=v"(r) : "v"(lo), "v"(hi));
    return r;
}

__global__ void prep_kernel(const float* __restrict__ W1, const float* __restrict__ b1,
                            const float* __restrict__ W2, const float* __restrict__ b2,
                            unsigned short* __restrict__ W1T,
                            float* __restrict__ b1F, float* __restrict__ w2F,
                            float* __restrict__ b2F)
{
    const int q = blockIdx.x, t = threadIdx.x;
    const int u = t & 31, s = t >> 5;
    W1T[(q * 32 + u) * 8 + s] = f2bf(W1[(q * 8 + s) * 32 + u]);
    if (t < 32) {
        int reg = t & 15, hh = t >> 4;
        int uu  = (reg & 3) + 8 * (reg >> 2) + 4 * hh;   // verified C/D row map
        b1F[(q * 2 + hh) * 16 + reg] = b1[q * 32 + uu] + 1.0f;
        w2F[(q * 2 + hh) * 16 + reg] = W2[q * 32 + uu];
    }
    if (t == 0) {
        float sw = 0.f;
        for (int uu = 0; uu < 32; ++uu) sw += W2[q * 32 + uu];
        b2F[q] = b2[q] - sw;
    }
}

__global__ __launch_bounds__(256)
__attribute__((amdgpu_waves_per_eu(3, 4)))
void divenc_pipe(const float* __restrict__ x, const unsigned short* __restrict__ W1T,
                 const float* __restrict__ b1F, const float* __restrict__ w2F,
                 const float* __restrict__ b2F, float* __restrict__ out, int B)
{
    __shared__ __align__(16) unsigned char xs[2 * XSBUF + 16];
    __shared__ __align__(16) float os[TROWS * OSS];

    const int t    = threadIdx.x;
    const int lane = t & 63;
    const int wv   = __builtin_amdgcn_readfirstlane(t >> 6);
    const int bl   = lane & 31;
    const int h    = lane >> 5;
    const bool lo  = (lane < 32);
    const int bid   = blockIdx.x;
    const int qb    = (bid & 15) * QW;
    const int rbase = (bid >> 4) * RPB;
    const int rmax  = B - 1;

    if (t == 0) *(uint4*)(xs + ZOFF) = uint4{0, 0, 0, 0};

    // ---- resident weights: wave wv owns qA, qB for the whole block ----
    const int qA = qb + wv * 2, qB = qA + 1;
    const uint4  axA  = *(const uint4*)(W1T + ((size_t)qA * 32 + bl) * 8);
    const uint4  axB  = *(const uint4*)(W1T + ((size_t)qB * 32 + bl) * 8);
    const f32x16 cinA = *(const f32x16*)(b1F + ((size_t)qA * 2 + h) * 16);
    const f32x16 cinB = *(const f32x16*)(b1F + ((size_t)qB * 2 + h) * 16);
    const f32x16 wrA  = *(const f32x16*)(w2F + ((size_t)qA * 2 + h) * 16);
    const f32x16 wrB  = *(const f32x16*)(w2F + ((size_t)qB * 2 + h) * 16);
    const float  b2A  = b2F[qA], b2B = b2F[qB];

    const f32x2 l2e2  = 1.44269504088896f;
    const f32x2 nl2e2 = -1.44269504088896f;
    const f32x2 zero2 = 0.0f;

    const int row0 = t >> 3,         qr0 = t & 7;
    const int row1 = (t + 256) >> 3, qr1 = t & 7;
    float4 pa0, pb0, pa1, pb1;

#define LOADT(T) {                                                                   \
    int r0_ = rbase + (T) * TROWS + row0; if (r0_ > rmax) r0_ = rmax;                \
    int r1_ = rbase + (T) * TROWS + row1; if (r1_ > rmax) r1_ = rmax;                \
    const float4* p0_ = (const float4*)(x + (size_t)r0_ * (Q * S)                    \
                                          + (size_t)(qb + qr0) * S);                 \
    const float4* p1_ = (const float4*)(x + (size_t)r1_ * (Q * S)                    \
                                          + (size_t)(qb + qr1) * S);                 \
    pa0 = p0_[0]; pb0 = p0_[1];                                                      \
    pa1 = p1_[0]; pb1 = p1_[1]; }

#define WRITET(XB) {                                                                 \
    uint4 w0_, w1_;                                                                  \
    w0_.x = cvt_pk_bf16(pa0.x, pa0.y); w0_.y = cvt_pk_bf16(pa0.z, pa0.w);            \
    w0_.z = cvt_pk_bf16(pb0.x, pb0.y); w0_.w = cvt_pk_bf16(pb0.z, pb0.w);            \
    w1_.x = cvt_pk_bf16(pa1.x, pa1.y); w1_.y = cvt_pk_bf16(pa1.z, pa1.w);            \
    w1_.z = cvt_pk_bf16(pb1.x, pb1.y); w1_.w = cvt_pk_bf16(pb1.z, pb1.w);            \
    *(uint4*)(xs + (XB) + row0 * RSTRIDE + qr0 * 16) = w0_;                          \
    *(uint4*)(xs + (XB) + row1 * RSTRIDE + qr1 * 16) = w1_; }

#define EL2(CC, J, WR, ACC) {                                                        \
    f32x2 v_; v_.x = CC[2*(J)]; v_.y = CC[2*(J)+1];                                  \
    f32x2 w2v; w2v.x = WR[2*(J)]; w2v.y = WR[2*(J)+1];                               \
    f32x2 f_ = __builtin_elementwise_fma(v_, l2e2, nl2e2);                           \
    f_ = __builtin_elementwise_min(f_, zero2);                                       \
    f32x2 e_; e_.x = __builtin_amdgcn_exp2f(f_.x);                                   \
    e_.y = __builtin_amdgcn_exp2f(f_.y);                                             \
    f32x2 r_ = __builtin_elementwise_max(v_, e_);                                    \
    ACC = __builtin_elementwise_fma(r_, w2v, ACC); }

#define COMP(AX, CIN, WR, B2, QR, XB) {                                              \
    const int xoff = (XB) + bl * RSTRIDE + (QR) * 16;                                \
    uint4 bx0 = *(const uint4*)(xs + (lo ? xoff                : ZOFF));             \
    uint4 bx1 = *(const uint4*)(xs + (lo ? xoff + 32 * RSTRIDE : ZOFF));             \
    f32x16 cc0 = __builtin_amdgcn_mfma_f32_32x32x16_bf16(                            \
        __builtin_bit_cast(bf16x8, AX), __builtin_bit_cast(bf16x8, bx0),             \
        CIN, 0, 0, 0);                                                               \
    f32x16 cc1 = __builtin_amdgcn_mfma_f32_32x32x16_bf16(                            \
        __builtin_bit_cast(bf16x8, AX), __builtin_bit_cast(bf16x8, bx1),             \
        CIN, 0, 0, 0);                                                               \
    f32x2 acc0 = 0.0f, acc1 = 0.0f;                                                  \
    EL2(cc0, 0, WR, acc0) EL2(cc0, 1, WR, acc0) EL2(cc0, 2, WR, acc0)                \
    EL2(cc0, 3, WR, acc0) EL2(cc0, 4, WR, acc0) EL2(cc0, 5, WR, acc0)                \
    EL2(cc0, 6, WR, acc0) EL2(cc0, 7, WR, acc0)                                      \
    EL2(cc1, 0, WR, acc1) EL2(cc1, 1, WR, acc1) EL2(cc1, 2, WR, acc1)                \
    EL2(cc1, 3, WR, acc1) EL2(cc1, 4, WR, acc1) EL2(cc1, 5, WR, acc1)                \
    EL2(cc1, 6, WR, acc1) EL2(cc1, 7, WR, acc1)                                      \
    float a0 = acc0.x + acc0.y;                                                      \
    float a1 = acc1.x + acc1.y;                                                      \
    a0 += __shfl_xor(a0, 32);                                                        \
    a1 += __shfl_xor(a1, 32);                                                        \
    if (lo) {                                                                        \
        os[bl * OSS + (QR)]        = a0 + (B2);                                      \
        os[(bl + 32) * OSS + (QR)] = a1 + (B2);                                      \
    } }

#define STORE(T) {                                                                   \
    if (t < 128) {                                                                   \
        int row_ = t >> 1, c_ = t & 1;                                               \
        float4 o_ = *(const float4*)&os[row_ * OSS + c_ * 4];                        \
        int r_ = rbase + (T) * TROWS + row_;                                         \
        if (r_ < B)                                                                  \
            *(float4*)(out + (size_t)r_ * Q + qb + c_ * 4) = o_;                     \
    } }

    // ---- prologue: tile 0 staged, tile 1 in flight ----
    LOADT(0) WRITET(0)
    LOADT(1)

    #pragma unroll 1
    for (int tile = 0; tile < NTILE; ++tile) {
        __syncthreads();                      // xs[tile&1] ready; os free
        if (tile + 1 < NTILE) WRITET(((tile + 1) & 1) * XSBUF)  // full-tile slack
        if (tile + 2 < NTILE) LOADT(tile + 2)                   // depth-2 prefetch
        COMP(axA, cinA, wrA, b2A, wv * 2,     (tile & 1) * XSBUF)
        COMP(axB, cinB, wrB, b2B, wv * 2 + 1, (tile & 1) * XSBUF)
        __syncthreads();                      // os complete; xs[tile&1] consumed
        STORE(tile)
    }
#undef LOADT
#undef WRITET
#undef EL2
#undef COMP
#undef STORE
}

extern "C" void kernel_launch(void* const* d_in, const int* in_sizes, int n_in,
                              void* d_out, int out_size, void* d_ws, size_t ws_size,
                              hipStream_t stream) {
    const float* x  = (const float*)d_in[0];
    const float* W1 = (const float*)d_in[1];
    const float* b1 = (const float*)d_in[2];
    const float* W2 = (const float*)d_in[3];
    const float* b2 = (const float*)d_in[4];
    float* out = (float*)d_out;

    unsigned short* W1T = (unsigned short*)d_ws;
    float*          b1F = (float*)((char*)d_ws + 65536);
    float*          w2F = (float*)((char*)d_ws + 81920);
    float*          b2F = (float*)((char*)d_ws + 98304);

    const int B = in_sizes[0] / (Q * S);
    const int nblocks = ((B + RPB - 1) / RPB) * (Q / QW);   // 1024

    hipLaunchKernelGGL(prep_kernel, dim3(Q), dim3(256), 0, stream,
                       W1, b1, W2, b2, W1T, b1F, w2F, b2F);
    hipLaunchKernelGGL(divenc_pipe, dim3(nblocks), dim3(256), 0, stream,
                       x, W1T, b1F, w2F, b2F, out, B);
}